// Round 2
// baseline (169.424 us; speedup 1.0000x reference)
//
#include <hip/hip_runtime.h>
#include <hip/hip_bf16.h>

// Problem constants: B=32, S=127, new_seq=128, D=768, H=12, HD=64
#define NB 32
#define NS 128     // new_seq
#define SD 127     // S
#define ND 768
#define NH 12
#define HD 64

__device__ inline float waveReduceSum(float v){
  #pragma unroll
  for (int off=32; off>0; off>>=1) v += __shfl_xor(v, off);
  return v;
}
__device__ inline float waveReduceMax(float v){
  #pragma unroll
  for (int off=32; off>0; off>>=1) v = fmaxf(v, __shfl_xor(v, off));
  return v;
}

// uk[h][c] = sum_d Wk[h*64+d, c] * wk_a[d]; bkdot[h] = bk_h . wk_a
__global__ void fold_k(const float* __restrict__ Wk, const float* __restrict__ bk,
                       const float* __restrict__ Wa, float* __restrict__ uk,
                       float* __restrict__ bkdot){
  int t = blockIdx.x*256 + threadIdx.x;       // 0..9215
  int h = t / ND, c = t % ND;
  const float* wka = Wa + 64;
  float acc = 0.f;
  #pragma unroll 8
  for (int d=0; d<64; ++d) acc += Wk[(h*64+d)*ND + c] * wka[d];
  uk[h*ND + c] = acc;
  if (blockIdx.x==0 && threadIdx.x < NH){
    int hh = threadIdx.x; float a = 0.f;
    for (int d=0; d<64; ++d) a += bk[hh*64+d]*wka[d];
    bkdot[hh] = a;
  }
}

// Fused: blocks [0,4096) -> lk rows; [4096, 8160) -> ei rows
__global__ void lk_ei_kernel(const float* __restrict__ nv, const float* __restrict__ desc,
                             const float* __restrict__ uk, const float* __restrict__ bkdot,
                             const float* __restrict__ Wa,
                             float* __restrict__ lk, float* __restrict__ ei){
  __shared__ float sh[ND];
  int blk = blockIdx.x;
  int wave = threadIdx.x >> 6, lane = threadIdx.x & 63;
  if (blk < NB*NS){
    int b = blk >> 7, j = blk & 127;
    const float* row = nv + (size_t)blk * ND;
    for (int c = threadIdx.x; c < ND; c += 256) sh[c] = row[c];
    __syncthreads();
    #pragma unroll
    for (int hh=0; hh<3; ++hh){
      int h = wave*3 + hh;
      float acc = 0.f;
      #pragma unroll
      for (int c = lane; c < ND; c += 64) acc += sh[c]*uk[h*ND + c];
      acc = waveReduceSum(acc);
      if (lane==0) lk[(b*NH + h)*NS + j] = acc + bkdot[h];
    }
  } else {
    int bs = blk - NB*NS;                 // 0..4063
    int b = bs / SD, s = bs % SD;
    float wea = Wa[128 + lane];
    const float* row = desc + (size_t)bs * ND;
    #pragma unroll
    for (int hh=0; hh<3; ++hh){
      int h = wave + hh*4;
      float v = row[h*64 + lane] * wea;
      v = waveReduceSum(v);
      if (lane==0) ei[(b*NH + h)*NS + s] = v;
    }
  }
}

// Per (b,h): two softmaxes -> w[bh][which][j] and transposed wT[b][j][r], r=h*2+which
__global__ void softmax_w(const float* __restrict__ lk, const float* __restrict__ ei,
                          float* __restrict__ w, float* __restrict__ wT){
  int bh = blockIdx.x;                // 0..383
  int b = bh / NH, h = bh % NH;
  __shared__ float s0[NS], s1[NS], w0[NS], w1[NS];
  int t = threadIdx.x;
  if (t < NS){
    float lkv = lk[bh*NS + t];
    float ehh = 0.f, eh6 = 0.f;
    if (t >= 1){
      ehh = ei[(b*NH + h)*NS + t-1];
      eh6 = ei[(b*NH + (h % 6))*NS + t-1];
    }
    s0[t] = lkv + eh6;
    s1[t] = lkv + (h >= 6 ? ehh : 0.f);
  }
  __syncthreads();
  int wave = t >> 6, lane = t & 63;
  if (wave < 2){
    float* s  = wave ? s1 : s0;
    float* wd = wave ? w1 : w0;
    float x0 = (lane >= 1) ? s[lane] : -3.0e38f;
    float x1 = s[lane + 64];
    float m = waveReduceMax(fmaxf(x0, x1));
    float e0 = (lane >= 1) ? expf(x0 - m) : 0.f;
    float e1 = expf(x1 - m);
    float sum = waveReduceSum(e0 + e1);
    float inv = 1.f / sum;
    wd[lane]      = e0 * inv;   // lane0 -> exactly 0 (masked col 0)
    wd[lane + 64] = e1 * inv;
  }
  __syncthreads();
  if (t < NS){
    w[(bh*2 + 0)*NS + t] = w0[t];
    w[(bh*2 + 1)*NS + t] = w1[t];
    wT[(b*NS + t)*24 + h*2 + 0] = w0[t];
    wT[(b*NS + t)*24 + h*2 + 1] = w1[t];
  }
}

// m[b][r][c] = sum_j wT[b][j][r] * nv[b][j][c]   (one pass over nv; w loads are
// thread-uniform -> scalar)
__global__ void m_kernel(const float* __restrict__ nv, const float* __restrict__ wT,
                         float* __restrict__ m){
  int b = blockIdx.x / 3, cc = blockIdx.x % 3;
  int c = cc*256 + threadIdx.x;
  const float* wtb = wT + b*NS*24;
  const float* nvb = nv + (size_t)b*NS*ND + c;
  float acc[24];
  #pragma unroll
  for (int r=0; r<24; ++r) acc[r] = 0.f;
  for (int j=1; j<NS; ++j){
    float nvv = nvb[(size_t)j*ND];
    const float* wj = wtb + j*24;
    #pragma unroll
    for (int r=0; r<24; ++r) acc[r] += wj[r]*nvv;
  }
  #pragma unroll
  for (int r=0; r<24; ++r) m[((size_t)b*24 + r)*ND + c] = acc[r];
}

// Per (b,h): ctx[b][h*2+which][d] = m[b][h*2+which][:] . Wv[h*64+d,:] + bv
__global__ void proj_kernel(const float* __restrict__ m, const float* __restrict__ Wv,
                            const float* __restrict__ bv, float* __restrict__ ctx){
  int bh = blockIdx.x;                // 0..383
  int b = bh / NH, h = bh % NH;
  int wave = threadIdx.x >> 6, lane = threadIdx.x & 63;
  const float* m0 = m + ((size_t)b*24 + h*2)*ND;
  const float* m1 = m0 + ND;
  #pragma unroll 4
  for (int dd=0; dd<16; ++dd){
    int d = wave*16 + dd;
    const float* wvrow = Wv + (size_t)(h*64 + d)*ND;
    float a0 = 0.f, a1 = 0.f;
    #pragma unroll
    for (int k=0; k<12; ++k){
      float wv = wvrow[lane + 64*k];
      a0 += m0[lane + 64*k]*wv;
      a1 += m1[lane + 64*k]*wv;
    }
    a0 = waveReduceSum(a0);
    a1 = waveReduceSum(a1);
    if (lane==0){
      float bb = bv[h*64 + d];
      ctx[((size_t)b*24 + h*2    )*HD + d] = a0 + bb;
      ctx[((size_t)b*24 + h*2 + 1)*HD + d] = a1 + bb;
    }
  }
}

// One float4 per thread: [0,786432) basis, [786432, 2359296) attn
__global__ void write_kernel(const float* __restrict__ ctx, const float* __restrict__ w,
                             float* __restrict__ out){
  int idx = blockIdx.x*256 + threadIdx.x;
  const float4* c4 = (const float4*)ctx;
  const float4* w4 = (const float4*)w;
  float4* o4 = (float4*)out;
  if (idx < 786432){
    int dq = idx & 15;
    int h  = (idx >> 4) % NH;
    int i  = (idx / 192) & 127;
    int b  = idx / 24576;
    o4[idx] = c4[((b*NH + h)*2 + (i != 0))*16 + dq];
  } else {
    int q  = idx - 786432;
    int j4 = q & 31;
    int i  = (q >> 5) & 127;
    int bh = q >> 12;
    o4[idx] = w4[(bh*2 + (i != 0))*32 + j4];
  }
}

extern "C" void kernel_launch(void* const* d_in, const int* in_sizes, int n_in,
                              void* d_out, int out_size, void* d_ws, size_t ws_size,
                              hipStream_t stream) {
  const float* desc = (const float*)d_in[0];
  const float* nv   = (const float*)d_in[1];
  // d_in[2] = Wq, d_in[3] = bq : unused (softmax shift-invariance)
  const float* Wk   = (const float*)d_in[4];
  const float* bk   = (const float*)d_in[5];
  const float* Wv   = (const float*)d_in[6];
  const float* bv   = (const float*)d_in[7];
  const float* Wa   = (const float*)d_in[8];
  // d_in[9] = ba : unused (constant shift)
  float* out = (float*)d_out;
  float* ws  = (float*)d_ws;

  float* uk    = ws;              // 9216
  float* bkdot = ws + 9216;       // 16
  float* ei    = ws + 9232;       // 49152
  float* lkbuf = ws + 58384;      // 49152
  float* wbuf  = ws + 107536;     // 98304   [bh][which][j]
  float* wT    = ws + 205840;     // 98304   [b][j][r]
  float* mbuf  = ws + 304144;     // 589824  [b][r][c]
  float* ctx   = ws + 893968;     // 49152   [b][r][d]

  fold_k      <<<36,    256, 0, stream>>>(Wk, bk, Wa, uk, bkdot);
  lk_ei_kernel<<<8160,  256, 0, stream>>>(nv, desc, uk, bkdot, Wa, lkbuf, ei);
  softmax_w   <<<384,   256, 0, stream>>>(lkbuf, ei, wbuf, wT);
  m_kernel    <<<96,    256, 0, stream>>>(nv, wT, mbuf);
  proj_kernel <<<384,   256, 0, stream>>>(mbuf, Wv, bv, ctx);
  write_kernel<<<9216,  256, 0, stream>>>(ctx, wbuf, out);
}